// Round 2
// baseline (37.120 us; speedup 1.0000x reference)
//
#include <hip/hip_runtime.h>

// Q_s_a[b] = relu(node_emb[idx[b]] * (state[b]·W4)) · W5
//
// 16 lanes per row; lane j holds elements [4j..4j+3] (one float4) of the
// 64-wide row -> every row access is a coalesced 256 B segment, a full wave
// covers 4 consecutive rows (1 KiB per load instruction).
//
// state/idx/out are streamed exactly once -> non-temporal (keep L2 for the
// 51 MB node table that the random gather re-reads). idx is prefetched one
// grid-stride iteration ahead to break the idx->gather dependent-load chain.

typedef float f4 __attribute__((ext_vector_type(4)));

__global__ __launch_bounds__(256) void Decoding_43404939493634_kernel(
    const int*   __restrict__ idx,    // [B]
    const float* __restrict__ node,   // [N, 64]
    const float* __restrict__ state,  // [B, 64]
    const float* __restrict__ W4,     // [64]
    const float* __restrict__ W5,     // [64]
    float*       __restrict__ out,    // [B]
    int B)
{
    const int lane16 = threadIdx.x & 15;

    const f4 w4 = reinterpret_cast<const f4*>(W4)[lane16];
    const f4 w5 = reinterpret_cast<const f4*>(W5)[lane16];

    const int group   = (blockIdx.x * blockDim.x + threadIdx.x) >> 4;
    const int ngroups = (gridDim.x * blockDim.x) >> 4;

    // Prefetch the first index.
    int a_next = (group < B) ? __builtin_nontemporal_load(idx + group) : 0;

    for (int row = group; row < B; row += ngroups) {
        const int a = a_next;
        const int nrow = row + ngroups;
        if (nrow < B) a_next = __builtin_nontemporal_load(idx + nrow);

        // Streamed row of state: non-temporal.
        const f4 se = __builtin_nontemporal_load(
            reinterpret_cast<const f4*>(state + (size_t)row * 64) + lane16);
        // Gathered node row: cached (L2/L3 reuse across repeated indices).
        const f4 ne = reinterpret_cast<const f4*>(node + (size_t)a * 64)[lane16];

        // s = dot(state_row, W4): per-lane partial, 4-step 16-lane reduce.
        float s = se.x * w4.x + se.y * w4.y + se.z * w4.z + se.w * w4.w;
        #pragma unroll
        for (int o = 1; o < 16; o <<= 1) s += __shfl_xor(s, o);

        // q = sum_e relu(node_row[e] * s) * W5[e]
        float q = fmaxf(ne.x * s, 0.f) * w5.x
                + fmaxf(ne.y * s, 0.f) * w5.y
                + fmaxf(ne.z * s, 0.f) * w5.z
                + fmaxf(ne.w * s, 0.f) * w5.w;
        #pragma unroll
        for (int o = 1; o < 16; o <<= 1) q += __shfl_xor(q, o);

        if (lane16 == 0)
            __builtin_nontemporal_store(q, out + row);
    }
}

extern "C" void kernel_launch(void* const* d_in, const int* in_sizes, int n_in,
                              void* d_out, int out_size, void* d_ws, size_t ws_size,
                              hipStream_t stream) {
    const int*   idx   = (const int*)  d_in[0];  // actions_idx     [B]
    const float* node  = (const float*)d_in[1];  // node_embedding  [N,64]
    const float* state = (const float*)d_in[2];  // state_embedding [B,64]
    const float* W4    = (const float*)d_in[3];  // [64,1]
    const float* W5    = (const float*)d_in[4];  // [64,1]
    float*       out   = (float*)d_out;          // [B,1]

    const int B = in_sizes[0];

    const int block  = 256;
    const int blocks = 2048;  // fills 256 CU * 8 blocks; grid-stride covers B
    Decoding_43404939493634_kernel<<<blocks, block, 0, stream>>>(
        idx, node, state, W4, W5, out, B);
}